// Round 3
// baseline (289.892 us; speedup 1.0000x reference)
//
#include <hip/hip_runtime.h>
#include <math.h>

// Fused MHA: B=2048, S=200, E=16, H=2, D=8, fp32 in/out.
// One block per batch element. LDS-resident Q/K/V/context + weights.

constexpr int S = 200;
constexpr int E = 16;
constexpr int D = 8;

__global__ __launch_bounds__(256, 2) void attn_fused(
    const float* __restrict__ in_q, const float* __restrict__ in_k,
    const float* __restrict__ in_v, const float* __restrict__ Wq,
    const float* __restrict__ Wk, const float* __restrict__ Wv,
    const float* __restrict__ Wfc, float* __restrict__ out)
{
    __shared__ float sQ[S][E];   // projected Q (scale folded in)
    __shared__ float sK[S][E];   // projected K (both heads side by side)
    __shared__ float sV[S][E];
    __shared__ float sC[S][E];   // attention context
    __shared__ float sW[3][E][E];  // W_Q, W_K, W_V  ([f][e], y[f]=sum_e x[e]*W[f][e])
    __shared__ float sWfc[E][E];

    const int tid = threadIdx.x;
    const long long b = blockIdx.x;

    // ---- load weights (each thread one element of each 16x16 weight) ----
    {
        const int f = tid >> 4, e = tid & 15;
        sW[0][f][e] = Wq[tid];
        sW[1][f][e] = Wk[tid];
        sW[2][f][e] = Wv[tid];
        sWfc[f][e]  = Wfc[tid];
    }
    __syncthreads();

    // ---- phase 1: QKV projections, 600 row-tasks over 256 threads ----
    for (int task = tid; task < 3 * S; task += 256) {
        const int t = task / S;          // 0=Q, 1=K, 2=V
        const int row = task - t * S;
        const float* src = (t == 0 ? in_q : (t == 1 ? in_k : in_v)) + (b * S + row) * E;
        float x[E];
        {
            float4* xv = (float4*)x;
            const float4* sv = (const float4*)src;
            xv[0] = sv[0]; xv[1] = sv[1]; xv[2] = sv[2]; xv[3] = sv[3];
        }
        float* dst = (t == 0 ? &sQ[row][0] : (t == 1 ? &sK[row][0] : &sV[row][0]));
        const float scl = (t == 0) ? 0.3535533905932738f : 1.0f;  // 1/sqrt(D) folded into Q
        #pragma unroll
        for (int f = 0; f < E; ++f) {
            float acc = 0.f;
            #pragma unroll
            for (int e = 0; e < E; ++e) acc = fmaf(x[e], sW[t][f][e], acc);
            dst[f] = acc * scl;
        }
    }
    __syncthreads();

    // ---- phase 2: online-softmax attention; thread t owns query row t, both heads ----
    if (tid < S) {
        float q0[D], q1[D];
        #pragma unroll
        for (int d = 0; d < D; ++d) { q0[d] = sQ[tid][d]; q1[d] = sQ[tid][D + d]; }
        float m0 = -1e30f, l0 = 0.f;
        float m1 = -1e30f, l1 = 0.f;
        float c0[D], c1[D];
        #pragma unroll
        for (int d = 0; d < D; ++d) { c0[d] = 0.f; c1[d] = 0.f; }

        for (int k = 0; k < S; ++k) {
            // broadcast LDS reads (all active lanes same address)
            const float4 ka = *(const float4*)&sK[k][0];
            const float4 kb = *(const float4*)&sK[k][4];
            const float4 kc = *(const float4*)&sK[k][8];
            const float4 kd = *(const float4*)&sK[k][12];
            const float4 va = *(const float4*)&sV[k][0];
            const float4 vb = *(const float4*)&sV[k][4];
            const float4 vc = *(const float4*)&sV[k][8];
            const float4 vd = *(const float4*)&sV[k][12];

            float s0 = fmaf(q0[0], ka.x, fmaf(q0[1], ka.y, fmaf(q0[2], ka.z, fmaf(q0[3], ka.w,
                       fmaf(q0[4], kb.x, fmaf(q0[5], kb.y, fmaf(q0[6], kb.z, q0[7] * kb.w)))))));
            float s1 = fmaf(q1[0], kc.x, fmaf(q1[1], kc.y, fmaf(q1[2], kc.z, fmaf(q1[3], kc.w,
                       fmaf(q1[4], kd.x, fmaf(q1[5], kd.y, fmaf(q1[6], kd.z, q1[7] * kd.w)))))));

            // single-exp online softmax update, head 0
            {
                const float d0 = s0 - m0;
                const float e0 = __expf(-fabsf(d0));
                const bool  g0 = d0 > 0.f;
                const float a0 = g0 ? e0 : 1.f;
                const float p0 = g0 ? 1.f : e0;
                m0 = g0 ? s0 : m0;
                l0 = fmaf(l0, a0, p0);
                c0[0] = fmaf(c0[0], a0, p0 * va.x);
                c0[1] = fmaf(c0[1], a0, p0 * va.y);
                c0[2] = fmaf(c0[2], a0, p0 * va.z);
                c0[3] = fmaf(c0[3], a0, p0 * va.w);
                c0[4] = fmaf(c0[4], a0, p0 * vb.x);
                c0[5] = fmaf(c0[5], a0, p0 * vb.y);
                c0[6] = fmaf(c0[6], a0, p0 * vb.z);
                c0[7] = fmaf(c0[7], a0, p0 * vb.w);
            }
            // head 1
            {
                const float d1 = s1 - m1;
                const float e1 = __expf(-fabsf(d1));
                const bool  g1 = d1 > 0.f;
                const float a1 = g1 ? e1 : 1.f;
                const float p1 = g1 ? 1.f : e1;
                m1 = g1 ? s1 : m1;
                l1 = fmaf(l1, a1, p1);
                c1[0] = fmaf(c1[0], a1, p1 * vc.x);
                c1[1] = fmaf(c1[1], a1, p1 * vc.y);
                c1[2] = fmaf(c1[2], a1, p1 * vc.z);
                c1[3] = fmaf(c1[3], a1, p1 * vc.w);
                c1[4] = fmaf(c1[4], a1, p1 * vd.x);
                c1[5] = fmaf(c1[5], a1, p1 * vd.y);
                c1[6] = fmaf(c1[6], a1, p1 * vd.z);
                c1[7] = fmaf(c1[7], a1, p1 * vd.w);
            }
        }
        const float i0 = 1.f / l0, i1 = 1.f / l1;
        #pragma unroll
        for (int d = 0; d < D; ++d) {
            sC[tid][d]     = c0[d] * i0;
            sC[tid][D + d] = c1[d] * i1;
        }
    }
    __syncthreads();

    // ---- phase 3: output projection + residual + ReLU ----
    if (tid < S) {
        float c[E];
        #pragma unroll
        for (int f = 0; f < E; ++f) c[f] = sC[tid][f];
        const float* qsrc = in_q + (b * S + tid) * E;
        float*       dst  = out  + (b * S + tid) * E;
        float xq[E];
        {
            float4* xv = (float4*)xq;
            const float4* sv = (const float4*)qsrc;
            xv[0] = sv[0]; xv[1] = sv[1]; xv[2] = sv[2]; xv[3] = sv[3];
        }
        float o[E];
        #pragma unroll
        for (int e = 0; e < E; ++e) {
            float acc = xq[e];
            #pragma unroll
            for (int f = 0; f < E; ++f) acc = fmaf(c[f], sWfc[e][f], acc);
            o[e] = fmaxf(acc, 0.f);
        }
        float4* ov = (float4*)o;
        float4* dv = (float4*)dst;
        dv[0] = ov[0]; dv[1] = ov[1]; dv[2] = ov[2]; dv[3] = ov[3];
    }
}

extern "C" void kernel_launch(void* const* d_in, const int* in_sizes, int n_in,
                              void* d_out, int out_size, void* d_ws, size_t ws_size,
                              hipStream_t stream) {
    const float* in_q = (const float*)d_in[0];
    const float* in_k = (const float*)d_in[1];
    const float* in_v = (const float*)d_in[2];
    const float* Wq   = (const float*)d_in[3];
    const float* Wk   = (const float*)d_in[4];
    const float* Wv   = (const float*)d_in[5];
    const float* Wfc  = (const float*)d_in[6];
    float* out = (float*)d_out;

    const int B = in_sizes[0] / (S * E);  // 2048
    attn_fused<<<dim3(B), dim3(256), 0, stream>>>(in_q, in_k, in_v, Wq, Wk, Wv, Wfc, out);
}